// Round 2
// baseline (849.598 us; speedup 1.0000x reference)
//
#include <hip/hip_runtime.h>
#include <hip/hip_bf16.h>

// Problem constants
#define NB     8
#define NPTS   4096
#define DIMC   64
#define KNN_K  8
#define NBLK   12

// ---------------------------------------------------------------------------
// Kernel 0: zero the stats buffers (13 stages x 128 floats) — ws is poisoned
// with 0xAA before every timed launch, so we must re-zero every call.
// ---------------------------------------------------------------------------
__global__ void zero_stats_kernel(float* __restrict__ stats) {
    int i = threadIdx.x + blockIdx.x * 256;
    if (i < 13 * 128) stats[i] = 0.0f;
}

// ---------------------------------------------------------------------------
// Kernel 1: transpose fp32 points [b][d][n] -> point-major P0[b][n][d],
// fused with stats[0] (per-channel sum / sumsq) accumulation.
// Grid: 8 b x 64 tiles of 64 points = 512 WGs, 256 threads.
// ---------------------------------------------------------------------------
__global__ __launch_bounds__(256) void cast_kernel(
        const float* __restrict__ pts,
        float* __restrict__ P0, float* __restrict__ stats0) {
    __shared__ __align__(16) float tr[64 * 65];      // [d][n] transpose tile (+1 pad)
    __shared__ float slotA[4 * 64], slotB[4 * 64];
    int wg = blockIdx.x;
    int b = wg >> 6;
    int n0 = (wg & 63) << 6;
    int tid = threadIdx.x;
    int lane6 = tid & 63;
    int grp = tid >> 6;              // 0..3

    // coalesced read along n; store transposed in LDS
    #pragma unroll
    for (int k = 0; k < 16; ++k) {
        int d = grp + (k << 2);
        float v = pts[(((size_t)((b << 6) + d)) << 12) + n0 + lane6];
        tr[d * 65 + lane6] = v;
    }
    __syncthreads();
    // write point-major rows (lane = channel), accumulate stats
    int c = lane6;
    float s = 0.0f, s2 = 0.0f;
    #pragma unroll
    for (int k = 0; k < 16; ++k) {
        int p = grp + (k << 2);
        float v = tr[c * 65 + p];
        P0[((size_t)((b << 12) + n0 + p)) * 64 + c] = v;
        s += v; s2 += v * v;
    }
    slotA[grp * 64 + c] = s;
    slotB[grp * 64 + c] = s2;
    __syncthreads();
    if (tid < 64) {
        float t = slotA[tid] + slotA[64 + tid] + slotA[128 + tid] + slotA[192 + tid];
        atomicAdd(&stats0[tid], t);
    } else if (tid < 128) {
        int cc = tid - 64;
        float t = slotB[cc] + slotB[64 + cc] + slotB[128 + cc] + slotB[192 + cc];
        atomicAdd(&stats0[64 + cc], t);
    }
}

// ---------------------------------------------------------------------------
// Kernel 2: brute-force 8-NN (self included). One WG = 128 queries of one
// batch; whole batch (x,y,z,sq) in LDS as float4 (64 KB), broadcast reads.
// d2 formula matches the numpy reference bit-for-bit: no fp contraction,
// sequential dot, d2 = (sq_i - 2*dot) + sq_j. Ties resolve to lower index
// (strict < while scanning j ascending), matching top_k stability.
// Grid: 8 b x 32 tiles = 256 WGs, 128 threads.
// ---------------------------------------------------------------------------
__global__ __launch_bounds__(128) void knn_kernel(
        const float* __restrict__ xyz, int* __restrict__ idx) {
#pragma clang fp contract(off)
    __shared__ __align__(16) float4 pts4[NPTS];      // 64 KB
    int wg = blockIdx.x;
    int b = wg >> 5;
    int q0 = (wg & 31) << 7;
    int tid = threadIdx.x;
    const float* xb = xyz + (size_t)b * 3 * NPTS;
    for (int k = 0; k < 32; ++k) {
        int j = tid + (k << 7);
        float x = xb[j];
        float y = xb[NPTS + j];
        float z = xb[2 * NPTS + j];
        float sq = (x * x + y * y) + z * z;
        pts4[j] = make_float4(x, y, z, sq);
    }
    __syncthreads();
    int q = q0 + tid;
    float4 qp = pts4[q];
    float bd[8]; int bi[8];
    #pragma unroll
    for (int t = 0; t < 8; ++t) { bd[t] = 3.4e38f; bi[t] = 0; }
    for (int j = 0; j < NPTS; ++j) {
        float4 p = pts4[j];
        float dot = (qp.x * p.x + qp.y * p.y) + qp.z * p.z;
        float d2 = (qp.w - 2.0f * dot) + p.w;
        if (d2 < bd[7]) {
            bd[7] = d2; bi[7] = j;
            #pragma unroll
            for (int t = 7; t >= 1; --t) {
                float a = bd[t - 1];
                if (bd[t] < a) {
                    bd[t - 1] = bd[t]; bd[t] = a;
                    int ti = bi[t - 1]; bi[t - 1] = bi[t]; bi[t] = ti;
                }
            }
        }
    }
    int* op = idx + ((size_t)(b * NPTS + q)) * 8;
    #pragma unroll
    for (int t = 0; t < 8; ++t) op[t] = bi[t];
}

// ---------------------------------------------------------------------------
// Kernel 3 (x12): one residual block, fully fused.
//   - scale/shift from previous stats (BN affine + gamma folded)
//   - gather: m[d][pt] = (h_self + sum_8 h_nb)/9, h = lrelu(p*scale+shift)
//     applied on the fly (P is point-major: each row = contiguous 256 B)
//   - GEMM 64x64 per point, fp32 VALU, 4x4 register tile
//   - residual add; write P_next; accumulate NEXT block's stats via
//     shuffle + LDS + global atomics (so no separate stats kernels)
//   - last block: write fp32 output in [b][d][n] layout via LDS transpose
// Grid: 8 b x 64 tiles of 64 points = 512 WGs, 256 threads. LDS ~40 KB.
// ---------------------------------------------------------------------------
__global__ __launch_bounds__(256) void block_kernel(
        const float* __restrict__ Pin, float* __restrict__ Pout,
        const float* __restrict__ statsIn, float* __restrict__ statsOut,
        const float* __restrict__ Wp, const float* __restrict__ Bp,
        const float* __restrict__ Gp, const float* __restrict__ Betap,
        const int* __restrict__ gidx, float* __restrict__ dout, int last) {
    __shared__ __align__(16) float Wt[64 * 68];      // W transposed: Wt[d][o]
    __shared__ __align__(16) float mt[64 * 68];      // m[d][pt]
    __shared__ __align__(16) int   idxl[64 * 8];
    __shared__ __align__(16) float scale_l[64], shift_l[64], bias_l[64];
    __shared__ float slot[4 * 128];

    int wg = blockIdx.x;
    int b = wg >> 6;
    int n0 = (wg & 63) << 6;
    int tid = threadIdx.x;

    // --- setup: W^T, idx tile, BN affine ---
    #pragma unroll
    for (int k = 0; k < 16; ++k) {
        int lin = tid + (k << 8);
        int o = lin >> 6, d = lin & 63;
        Wt[d * 68 + o] = Wp[lin];
    }
    if (tid < 128) {
        ((int4*)idxl)[tid] = ((const int4*)(gidx + ((size_t)(b * NPTS + n0)) * 8))[tid];
    }
    if (tid < 64) {
        int c = tid;
        float sum = statsIn[c], sumsq = statsIn[64 + c];
        float mean = sum * (1.0f / 32768.0f);
        float var  = sumsq * (1.0f / 32768.0f) - mean * mean;
        float rs   = 1.0f / sqrtf(var + 1e-5f);
        float sc   = Gp[c] * rs;
        scale_l[c] = sc;
        shift_l[c] = Betap[c] - mean * sc;
        bias_l[c]  = Bp[c];
    }
    __syncthreads();

    // --- gather: m[d][pt] ---
    {
        int c = tid & 63, g = tid >> 6;
        float sc = scale_l[c], sh = shift_l[c];
        const float* Pb = Pin + (((size_t)b) << 12) * 64;
        #pragma unroll 2
        for (int p = 0; p < 16; ++p) {
            int pt = (g << 4) + p;
            float v = Pb[((size_t)(n0 + pt)) * 64 + c];
            float h = v * sc + sh; h = (h >= 0.0f) ? h : 0.01f * h;
            float acc = h;
            int4 ja = *(const int4*)&idxl[pt * 8];
            int4 jb = *(const int4*)&idxl[pt * 8 + 4];
            float u;
            u = Pb[((size_t)ja.x) * 64 + c]; u = u * sc + sh; acc += (u >= 0.f) ? u : 0.01f * u;
            u = Pb[((size_t)ja.y) * 64 + c]; u = u * sc + sh; acc += (u >= 0.f) ? u : 0.01f * u;
            u = Pb[((size_t)ja.z) * 64 + c]; u = u * sc + sh; acc += (u >= 0.f) ? u : 0.01f * u;
            u = Pb[((size_t)ja.w) * 64 + c]; u = u * sc + sh; acc += (u >= 0.f) ? u : 0.01f * u;
            u = Pb[((size_t)jb.x) * 64 + c]; u = u * sc + sh; acc += (u >= 0.f) ? u : 0.01f * u;
            u = Pb[((size_t)jb.y) * 64 + c]; u = u * sc + sh; acc += (u >= 0.f) ? u : 0.01f * u;
            u = Pb[((size_t)jb.z) * 64 + c]; u = u * sc + sh; acc += (u >= 0.f) ? u : 0.01f * u;
            u = Pb[((size_t)jb.w) * 64 + c]; u = u * sc + sh; acc += (u >= 0.f) ? u : 0.01f * u;
            mt[c * 68 + pt] = acc * (1.0f / 9.0f);
        }
    }
    __syncthreads();

    // --- GEMM: out[pt][o] = sum_d Wt[d][o] * m[d][pt] + bias[o] ---
    int o0 = (tid & 15) << 2;
    int p0 = (tid >> 4) << 2;
    float4 acc[4];
    {
        float4 bias4 = *(const float4*)&bias_l[o0];
        acc[0] = bias4; acc[1] = bias4; acc[2] = bias4; acc[3] = bias4;
    }
    #pragma unroll
    for (int d = 0; d < 64; ++d) {
        float4 wv = *(const float4*)&Wt[d * 68 + o0];
        float4 a  = *(const float4*)&mt[d * 68 + p0];
        acc[0].x += wv.x * a.x; acc[0].y += wv.y * a.x; acc[0].z += wv.z * a.x; acc[0].w += wv.w * a.x;
        acc[1].x += wv.x * a.y; acc[1].y += wv.y * a.y; acc[1].z += wv.z * a.y; acc[1].w += wv.w * a.y;
        acc[2].x += wv.x * a.z; acc[2].y += wv.y * a.z; acc[2].z += wv.z * a.z; acc[2].w += wv.w * a.z;
        acc[3].x += wv.x * a.w; acc[3].y += wv.y * a.w; acc[3].z += wv.z * a.w; acc[3].w += wv.w * a.w;
    }

    // --- residual add ---
    const float* PbIn = Pin + ((((size_t)b) << 12) + n0) * 64;
    #pragma unroll
    for (int j = 0; j < 4; ++j) {
        float4 r = *(const float4*)&PbIn[((size_t)(p0 + j)) * 64 + o0];
        acc[j].x += r.x; acc[j].y += r.y; acc[j].z += r.z; acc[j].w += r.w;
    }

    if (!last) {
        float* PbOut = Pout + ((((size_t)b) << 12) + n0) * 64;
        #pragma unroll
        for (int j = 0; j < 4; ++j)
            *(float4*)&PbOut[((size_t)(p0 + j)) * 64 + o0] = acc[j];

        // next block's stats: per-thread sums over 4 pts, shuffle-reduce the
        // 4 pt-groups within the wave (lanes ^16, ^32 share the o-quad)
        float4 s, s2;
        s.x = acc[0].x + acc[1].x + acc[2].x + acc[3].x;
        s.y = acc[0].y + acc[1].y + acc[2].y + acc[3].y;
        s.z = acc[0].z + acc[1].z + acc[2].z + acc[3].z;
        s.w = acc[0].w + acc[1].w + acc[2].w + acc[3].w;
        s2.x = acc[0].x*acc[0].x + acc[1].x*acc[1].x + acc[2].x*acc[2].x + acc[3].x*acc[3].x;
        s2.y = acc[0].y*acc[0].y + acc[1].y*acc[1].y + acc[2].y*acc[2].y + acc[3].y*acc[3].y;
        s2.z = acc[0].z*acc[0].z + acc[1].z*acc[1].z + acc[2].z*acc[2].z + acc[3].z*acc[3].z;
        s2.w = acc[0].w*acc[0].w + acc[1].w*acc[1].w + acc[2].w*acc[2].w + acc[3].w*acc[3].w;
        #pragma unroll
        for (int m = 16; m <= 32; m <<= 1) {
            s.x += __shfl_xor(s.x, m, 64);  s.y += __shfl_xor(s.y, m, 64);
            s.z += __shfl_xor(s.z, m, 64);  s.w += __shfl_xor(s.w, m, 64);
            s2.x += __shfl_xor(s2.x, m, 64); s2.y += __shfl_xor(s2.y, m, 64);
            s2.z += __shfl_xor(s2.z, m, 64); s2.w += __shfl_xor(s2.w, m, 64);
        }
        if ((tid & 63) < 16) {
            int w = tid >> 6;
            slot[w * 128 + o0 + 0] = s.x;  slot[w * 128 + o0 + 1] = s.y;
            slot[w * 128 + o0 + 2] = s.z;  slot[w * 128 + o0 + 3] = s.w;
            slot[w * 128 + 64 + o0 + 0] = s2.x; slot[w * 128 + 64 + o0 + 1] = s2.y;
            slot[w * 128 + 64 + o0 + 2] = s2.z; slot[w * 128 + 64 + o0 + 3] = s2.w;
        }
        __syncthreads();
        if (tid < 128) {
            float t = slot[tid] + slot[128 + tid] + slot[256 + tid] + slot[384 + tid];
            atomicAdd(&statsOut[tid], t);
        }
    } else {
        // write fp32 output in [b][o][n] layout via LDS-staged transpose
        __syncthreads();                         // all mt reads done
        float* stage = mt;                       // reuse as [o][pt], 16 KB
        #pragma unroll
        for (int j = 0; j < 4; ++j) {
            stage[(o0 + 0) * 64 + p0 + j] = acc[j].x;
            stage[(o0 + 1) * 64 + p0 + j] = acc[j].y;
            stage[(o0 + 2) * 64 + p0 + j] = acc[j].z;
            stage[(o0 + 3) * 64 + p0 + j] = acc[j].w;
        }
        __syncthreads();
        #pragma unroll
        for (int k = 0; k < 16; ++k) {
            int lin = tid + (k << 8);
            int o = lin >> 6, pt = lin & 63;
            dout[(((size_t)((b << 6) + o)) << 12) + n0 + pt] = stage[lin];
        }
    }
}

// ---------------------------------------------------------------------------
extern "C" void kernel_launch(void* const* d_in, const int* in_sizes, int n_in,
                              void* d_out, int out_size, void* d_ws, size_t ws_size,
                              hipStream_t stream) {
    const float* xyz    = (const float*)d_in[0];
    const float* pts    = (const float*)d_in[1];
    const float* conv_w = (const float*)d_in[2];
    const float* conv_b = (const float*)d_in[3];
    const float* gamma  = (const float*)d_in[4];
    const float* beta   = (const float*)d_in[5];
    float* out = (float*)d_out;

    char* ws = (char*)d_ws;
    float* P0   = (float*)(ws);                                  //  8 MB
    float* P1   = (float*)(ws + (size_t)8 * 1024 * 1024);        //  8 MB
    int*   idx  = (int*)  (ws + (size_t)16 * 1024 * 1024);       //  1 MB
    float* stats = (float*)(ws + (size_t)17 * 1024 * 1024);      // 13*128 floats

    zero_stats_kernel<<<7, 256, 0, stream>>>(stats);
    cast_kernel<<<512, 256, 0, stream>>>(pts, P0, stats);
    knn_kernel<<<256, 128, 0, stream>>>(xyz, idx);

    float* Pbuf[2] = {P0, P1};
    for (int t = 0; t < NBLK; ++t) {
        block_kernel<<<512, 256, 0, stream>>>(
            Pbuf[t & 1], Pbuf[(t + 1) & 1],
            stats + t * 128, stats + (t + 1) * 128,
            conv_w + (size_t)t * 4096, conv_b + (size_t)t * 64,
            gamma + (size_t)t * 64, beta + (size_t)t * 64,
            idx, out, (t == NBLK - 1) ? 1 : 0);
    }
}

// Round 3
// 581.888 us; speedup vs baseline: 1.4601x; 1.4601x over previous
//
#include <hip/hip_runtime.h>
#include <hip/hip_bf16.h>

// Problem constants
#define NB     8
#define NPTS   4096
#define DIMC   64
#define KNN_K  8
#define NBLK   12

// ---------------------------------------------------------------------------
// Kernel 0: zero the stats buffers (13 stages x 128 floats) — ws is poisoned
// with 0xAA before every timed launch, so we must re-zero every call.
// ---------------------------------------------------------------------------
__global__ void zero_stats_kernel(float* __restrict__ stats) {
    int i = threadIdx.x + blockIdx.x * 256;
    if (i < 13 * 128) stats[i] = 0.0f;
}

// ---------------------------------------------------------------------------
// Kernel 1: transpose fp32 points [b][d][n] -> point-major P0[b][n][d],
// fused with stats[0] (per-channel sum / sumsq) accumulation.
// Grid: 8 b x 64 tiles of 64 points = 512 WGs, 256 threads.
// ---------------------------------------------------------------------------
__global__ __launch_bounds__(256) void cast_kernel(
        const float* __restrict__ pts,
        float* __restrict__ P0, float* __restrict__ stats0) {
    __shared__ __align__(16) float tr[64 * 65];      // [d][n] transpose tile (+1 pad)
    __shared__ float slotA[4 * 64], slotB[4 * 64];
    int wg = blockIdx.x;
    int b = wg >> 6;
    int n0 = (wg & 63) << 6;
    int tid = threadIdx.x;
    int lane6 = tid & 63;
    int grp = tid >> 6;              // 0..3

    // coalesced read along n; store transposed in LDS
    #pragma unroll
    for (int k = 0; k < 16; ++k) {
        int d = grp + (k << 2);
        float v = pts[(((size_t)((b << 6) + d)) << 12) + n0 + lane6];
        tr[d * 65 + lane6] = v;
    }
    __syncthreads();
    // write point-major rows (lane = channel), accumulate stats
    int c = lane6;
    float s = 0.0f, s2 = 0.0f;
    #pragma unroll
    for (int k = 0; k < 16; ++k) {
        int p = grp + (k << 2);
        float v = tr[c * 65 + p];
        P0[((size_t)((b << 12) + n0 + p)) * 64 + c] = v;
        s += v; s2 += v * v;
    }
    slotA[grp * 64 + c] = s;
    slotB[grp * 64 + c] = s2;
    __syncthreads();
    if (tid < 64) {
        float t = slotA[tid] + slotA[64 + tid] + slotA[128 + tid] + slotA[192 + tid];
        atomicAdd(&stats0[tid], t);
    } else if (tid < 128) {
        int cc = tid - 64;
        float t = slotB[cc] + slotB[64 + cc] + slotB[128 + cc] + slotB[192 + cc];
        atomicAdd(&stats0[64 + cc], t);
    }
}

// ---------------------------------------------------------------------------
// Kernel 2: brute-force 8-NN (self included), chunk-parallel.
// One WG = 128 queries x 4 j-chunks (512 threads, 8 waves). Whole batch
// (x,y,z,sq) in LDS (64 KB, broadcast reads). Each thread scans a 1024-pt
// chunk with 8x-unrolled distance batch (8 ds_reads in flight -> ILP hides
// LDS latency), keeping a private sorted top-8. The 4 partial lists per
// query are 4-way merged lexicographically by (d2, idx) — identical result
// to a single ascending-j scan, matching top_k tie stability.
// d2 formula matches the numpy reference bit-for-bit: no fp contraction,
// sequential dot, d2 = (sq_i - 2*dot) + sq_j.
// Grid: 8 b x 32 tiles = 256 WGs, 512 threads. LDS ~98 KB -> 8 waves/CU.
// ---------------------------------------------------------------------------
__global__ __launch_bounds__(512) void knn_kernel(
        const float* __restrict__ xyz, int* __restrict__ idx) {
#pragma clang fp contract(off)
    __shared__ __align__(16) float4 pts4[NPTS];      // 64 KB
    __shared__ float pd[128 * 33];                   // partial dists, +1 pad
    __shared__ int   pi[128 * 33];                   // partial indices
    int wg = blockIdx.x;
    int b = wg >> 5;
    int q0 = (wg & 31) << 7;
    int tid = threadIdx.x;                           // 0..511
    const float* xb = xyz + (size_t)b * 3 * NPTS;
    #pragma unroll
    for (int k = 0; k < 8; ++k) {
        int j = tid + (k << 9);
        float x = xb[j];
        float y = xb[NPTS + j];
        float z = xb[2 * NPTS + j];
        float sq = (x * x + y * y) + z * z;
        pts4[j] = make_float4(x, y, z, sq);
    }
    __syncthreads();

    int ql = tid & 127;              // query within tile
    int ch = tid >> 7;               // j-chunk 0..3
    int q  = q0 + ql;
    float4 qp = pts4[q];
    float bd[8]; int bi[8];
    #pragma unroll
    for (int t = 0; t < 8; ++t) { bd[t] = 3.4e38f; bi[t] = 0x7fffffff; }

    int jbase = ch << 10;
    for (int jo = 0; jo < 1024; jo += 8) {
        float d2v[8];
        #pragma unroll
        for (int u = 0; u < 8; ++u) {
            float4 p = pts4[jbase + jo + u];
            float dot = (qp.x * p.x + qp.y * p.y) + qp.z * p.z;
            d2v[u] = (qp.w - 2.0f * dot) + p.w;
        }
        #pragma unroll
        for (int u = 0; u < 8; ++u) {
            float d2 = d2v[u];
            if (d2 < bd[7]) {
                bd[7] = d2; bi[7] = jbase + jo + u;
                #pragma unroll
                for (int t = 7; t >= 1; --t) {
                    float a = bd[t - 1];
                    if (bd[t] < a) {
                        bd[t - 1] = bd[t]; bd[t] = a;
                        int ti = bi[t - 1]; bi[t - 1] = bi[t]; bi[t] = ti;
                    }
                }
            }
        }
    }

    // stash partial top-8 (sorted asc; within-chunk ties keep lower j)
    {
        int base = ql * 33 + ch * 8;
        #pragma unroll
        for (int t = 0; t < 8; ++t) { pd[base + t] = bd[t]; pi[base + t] = bi[t]; }
    }
    __syncthreads();

    // 4-way merge per query (threads 0..127)
    if (tid < 128) {
        int qq = tid;
        int base = qq * 33;
        int head0 = 0, head1 = 8, head2 = 16, head3 = 24;
        int* op = idx + ((size_t)(b * NPTS + q0 + qq)) * 8;
        #pragma unroll
        for (int t = 0; t < 8; ++t) {
            float best = 3.4e38f; int bidx = 0x7fffffff; int bc = 0;
            {
                float d = pd[base + head0]; int i = pi[base + head0];
                if (d < best || (d == best && i < bidx)) { best = d; bidx = i; bc = 0; }
            }
            {
                float d = pd[base + head1]; int i = pi[base + head1];
                if (d < best || (d == best && i < bidx)) { best = d; bidx = i; bc = 1; }
            }
            {
                float d = pd[base + head2]; int i = pi[base + head2];
                if (d < best || (d == best && i < bidx)) { best = d; bidx = i; bc = 2; }
            }
            {
                float d = pd[base + head3]; int i = pi[base + head3];
                if (d < best || (d == best && i < bidx)) { best = d; bidx = i; bc = 3; }
            }
            head0 += (bc == 0); head1 += (bc == 1);
            head2 += (bc == 2); head3 += (bc == 3);
            op[t] = bidx;
        }
    }
}

// ---------------------------------------------------------------------------
// Kernel 3 (x12): one residual block, fully fused.
//   - scale/shift from previous stats (BN affine + gamma folded)
//   - gather: m[d][pt] = (h_self + sum_8 h_nb)/9, h = lrelu(p*scale+shift)
//     applied on the fly (P is point-major: each row = contiguous 256 B)
//   - GEMM 64x64 per point, fp32 VALU, 4x4 register tile
//   - residual add; write P_next; accumulate NEXT block's stats via
//     shuffle + LDS + global atomics (so no separate stats kernels)
//   - last block: write fp32 output in [b][d][n] layout via LDS transpose
// Grid: 8 b x 64 tiles of 64 points = 512 WGs, 256 threads. LDS ~40 KB.
// ---------------------------------------------------------------------------
__global__ __launch_bounds__(256) void block_kernel(
        const float* __restrict__ Pin, float* __restrict__ Pout,
        const float* __restrict__ statsIn, float* __restrict__ statsOut,
        const float* __restrict__ Wp, const float* __restrict__ Bp,
        const float* __restrict__ Gp, const float* __restrict__ Betap,
        const int* __restrict__ gidx, float* __restrict__ dout, int last) {
    __shared__ __align__(16) float Wt[64 * 68];      // W transposed: Wt[d][o]
    __shared__ __align__(16) float mt[64 * 68];      // m[d][pt]
    __shared__ __align__(16) int   idxl[64 * 8];
    __shared__ __align__(16) float scale_l[64], shift_l[64], bias_l[64];
    __shared__ float slot[4 * 128];

    int wg = blockIdx.x;
    int b = wg >> 6;
    int n0 = (wg & 63) << 6;
    int tid = threadIdx.x;

    // --- setup: W^T, idx tile, BN affine ---
    #pragma unroll
    for (int k = 0; k < 16; ++k) {
        int lin = tid + (k << 8);
        int o = lin >> 6, d = lin & 63;
        Wt[d * 68 + o] = Wp[lin];
    }
    if (tid < 128) {
        ((int4*)idxl)[tid] = ((const int4*)(gidx + ((size_t)(b * NPTS + n0)) * 8))[tid];
    }
    if (tid < 64) {
        int c = tid;
        float sum = statsIn[c], sumsq = statsIn[64 + c];
        float mean = sum * (1.0f / 32768.0f);
        float var  = sumsq * (1.0f / 32768.0f) - mean * mean;
        float rs   = 1.0f / sqrtf(var + 1e-5f);
        float sc   = Gp[c] * rs;
        scale_l[c] = sc;
        shift_l[c] = Betap[c] - mean * sc;
        bias_l[c]  = Bp[c];
    }
    __syncthreads();

    // --- gather: m[d][pt] ---
    {
        int c = tid & 63, g = tid >> 6;
        float sc = scale_l[c], sh = shift_l[c];
        const float* Pb = Pin + (((size_t)b) << 12) * 64;
        #pragma unroll 2
        for (int p = 0; p < 16; ++p) {
            int pt = (g << 4) + p;
            float v = Pb[((size_t)(n0 + pt)) * 64 + c];
            float h = v * sc + sh; h = (h >= 0.0f) ? h : 0.01f * h;
            float acc = h;
            int4 ja = *(const int4*)&idxl[pt * 8];
            int4 jb = *(const int4*)&idxl[pt * 8 + 4];
            float u;
            u = Pb[((size_t)ja.x) * 64 + c]; u = u * sc + sh; acc += (u >= 0.f) ? u : 0.01f * u;
            u = Pb[((size_t)ja.y) * 64 + c]; u = u * sc + sh; acc += (u >= 0.f) ? u : 0.01f * u;
            u = Pb[((size_t)ja.z) * 64 + c]; u = u * sc + sh; acc += (u >= 0.f) ? u : 0.01f * u;
            u = Pb[((size_t)ja.w) * 64 + c]; u = u * sc + sh; acc += (u >= 0.f) ? u : 0.01f * u;
            u = Pb[((size_t)jb.x) * 64 + c]; u = u * sc + sh; acc += (u >= 0.f) ? u : 0.01f * u;
            u = Pb[((size_t)jb.y) * 64 + c]; u = u * sc + sh; acc += (u >= 0.f) ? u : 0.01f * u;
            u = Pb[((size_t)jb.z) * 64 + c]; u = u * sc + sh; acc += (u >= 0.f) ? u : 0.01f * u;
            u = Pb[((size_t)jb.w) * 64 + c]; u = u * sc + sh; acc += (u >= 0.f) ? u : 0.01f * u;
            mt[c * 68 + pt] = acc * (1.0f / 9.0f);
        }
    }
    __syncthreads();

    // --- GEMM: out[pt][o] = sum_d Wt[d][o] * m[d][pt] + bias[o] ---
    int o0 = (tid & 15) << 2;
    int p0 = (tid >> 4) << 2;
    float4 acc[4];
    {
        float4 bias4 = *(const float4*)&bias_l[o0];
        acc[0] = bias4; acc[1] = bias4; acc[2] = bias4; acc[3] = bias4;
    }
    #pragma unroll
    for (int d = 0; d < 64; ++d) {
        float4 wv = *(const float4*)&Wt[d * 68 + o0];
        float4 a  = *(const float4*)&mt[d * 68 + p0];
        acc[0].x += wv.x * a.x; acc[0].y += wv.y * a.x; acc[0].z += wv.z * a.x; acc[0].w += wv.w * a.x;
        acc[1].x += wv.x * a.y; acc[1].y += wv.y * a.y; acc[1].z += wv.z * a.y; acc[1].w += wv.w * a.y;
        acc[2].x += wv.x * a.z; acc[2].y += wv.y * a.z; acc[2].z += wv.z * a.z; acc[2].w += wv.w * a.z;
        acc[3].x += wv.x * a.w; acc[3].y += wv.y * a.w; acc[3].z += wv.z * a.w; acc[3].w += wv.w * a.w;
    }

    // --- residual add ---
    const float* PbIn = Pin + ((((size_t)b) << 12) + n0) * 64;
    #pragma unroll
    for (int j = 0; j < 4; ++j) {
        float4 r = *(const float4*)&PbIn[((size_t)(p0 + j)) * 64 + o0];
        acc[j].x += r.x; acc[j].y += r.y; acc[j].z += r.z; acc[j].w += r.w;
    }

    if (!last) {
        float* PbOut = Pout + ((((size_t)b) << 12) + n0) * 64;
        #pragma unroll
        for (int j = 0; j < 4; ++j)
            *(float4*)&PbOut[((size_t)(p0 + j)) * 64 + o0] = acc[j];

        // next block's stats: per-thread sums over 4 pts, shuffle-reduce the
        // 4 pt-groups within the wave (lanes ^16, ^32 share the o-quad)
        float4 s, s2;
        s.x = acc[0].x + acc[1].x + acc[2].x + acc[3].x;
        s.y = acc[0].y + acc[1].y + acc[2].y + acc[3].y;
        s.z = acc[0].z + acc[1].z + acc[2].z + acc[3].z;
        s.w = acc[0].w + acc[1].w + acc[2].w + acc[3].w;
        s2.x = acc[0].x*acc[0].x + acc[1].x*acc[1].x + acc[2].x*acc[2].x + acc[3].x*acc[3].x;
        s2.y = acc[0].y*acc[0].y + acc[1].y*acc[1].y + acc[2].y*acc[2].y + acc[3].y*acc[3].y;
        s2.z = acc[0].z*acc[0].z + acc[1].z*acc[1].z + acc[2].z*acc[2].z + acc[3].z*acc[3].z;
        s2.w = acc[0].w*acc[0].w + acc[1].w*acc[1].w + acc[2].w*acc[2].w + acc[3].w*acc[3].w;
        #pragma unroll
        for (int m = 16; m <= 32; m <<= 1) {
            s.x += __shfl_xor(s.x, m, 64);  s.y += __shfl_xor(s.y, m, 64);
            s.z += __shfl_xor(s.z, m, 64);  s.w += __shfl_xor(s.w, m, 64);
            s2.x += __shfl_xor(s2.x, m, 64); s2.y += __shfl_xor(s2.y, m, 64);
            s2.z += __shfl_xor(s2.z, m, 64); s2.w += __shfl_xor(s2.w, m, 64);
        }
        if ((tid & 63) < 16) {
            int w = tid >> 6;
            slot[w * 128 + o0 + 0] = s.x;  slot[w * 128 + o0 + 1] = s.y;
            slot[w * 128 + o0 + 2] = s.z;  slot[w * 128 + o0 + 3] = s.w;
            slot[w * 128 + 64 + o0 + 0] = s2.x; slot[w * 128 + 64 + o0 + 1] = s2.y;
            slot[w * 128 + 64 + o0 + 2] = s2.z; slot[w * 128 + 64 + o0 + 3] = s2.w;
        }
        __syncthreads();
        if (tid < 128) {
            float t = slot[tid] + slot[128 + tid] + slot[256 + tid] + slot[384 + tid];
            atomicAdd(&statsOut[tid], t);
        }
    } else {
        // write fp32 output in [b][o][n] layout via LDS-staged transpose
        __syncthreads();                         // all mt reads done
        float* stage = mt;                       // reuse as [o][pt], 16 KB
        #pragma unroll
        for (int j = 0; j < 4; ++j) {
            stage[(o0 + 0) * 64 + p0 + j] = acc[j].x;
            stage[(o0 + 1) * 64 + p0 + j] = acc[j].y;
            stage[(o0 + 2) * 64 + p0 + j] = acc[j].z;
            stage[(o0 + 3) * 64 + p0 + j] = acc[j].w;
        }
        __syncthreads();
        #pragma unroll
        for (int k = 0; k < 16; ++k) {
            int lin = tid + (k << 8);
            int o = lin >> 6, pt = lin & 63;
            dout[(((size_t)((b << 6) + o)) << 12) + n0 + pt] = stage[lin];
        }
    }
}

// ---------------------------------------------------------------------------
extern "C" void kernel_launch(void* const* d_in, const int* in_sizes, int n_in,
                              void* d_out, int out_size, void* d_ws, size_t ws_size,
                              hipStream_t stream) {
    const float* xyz    = (const float*)d_in[0];
    const float* pts    = (const float*)d_in[1];
    const float* conv_w = (const float*)d_in[2];
    const float* conv_b = (const float*)d_in[3];
    const float* gamma  = (const float*)d_in[4];
    const float* beta   = (const float*)d_in[5];
    float* out = (float*)d_out;

    char* ws = (char*)d_ws;
    float* P0   = (float*)(ws);                                  //  8 MB
    float* P1   = (float*)(ws + (size_t)8 * 1024 * 1024);        //  8 MB
    int*   idx  = (int*)  (ws + (size_t)16 * 1024 * 1024);       //  1 MB
    float* stats = (float*)(ws + (size_t)17 * 1024 * 1024);      // 13*128 floats

    zero_stats_kernel<<<7, 256, 0, stream>>>(stats);
    cast_kernel<<<512, 256, 0, stream>>>(pts, P0, stats);
    knn_kernel<<<256, 512, 0, stream>>>(xyz, idx);

    float* Pbuf[2] = {P0, P1};
    for (int t = 0; t < NBLK; ++t) {
        block_kernel<<<512, 256, 0, stream>>>(
            Pbuf[t & 1], Pbuf[(t + 1) & 1],
            stats + t * 128, stats + (t + 1) * 128,
            conv_w + (size_t)t * 4096, conv_b + (size_t)t * 64,
            gamma + (size_t)t * 64, beta + (size_t)t * 64,
            idx, out, (t == NBLK - 1) ? 1 : 0);
    }
}

// Round 4
// 481.770 us; speedup vs baseline: 1.7635x; 1.2078x over previous
//
#include <hip/hip_runtime.h>
#include <hip/hip_bf16.h>

// Problem constants
#define NB     8
#define NPTS   4096
#define DIMC   64
#define KNN_K  8
#define NBLK   12

// ---------------------------------------------------------------------------
// Kernel 0: zero the stats buffers (13 stages x 128 floats) — ws is poisoned
// with 0xAA before every timed launch, so we must re-zero every call.
// ---------------------------------------------------------------------------
__global__ void zero_stats_kernel(float* __restrict__ stats) {
    int i = threadIdx.x + blockIdx.x * 256;
    if (i < 13 * 128) stats[i] = 0.0f;
}

// ---------------------------------------------------------------------------
// Kernel 0b: precompute (x, y, z, |x|^2) per point for the KNN kernel.
// sq formula matches numpy bit-for-bit (contract off, sequential adds).
// Grid: 32768 / 256 = 128 WGs.
// ---------------------------------------------------------------------------
__global__ __launch_bounds__(256) void prep_kernel(
        const float* __restrict__ xyz, float4* __restrict__ pts4g) {
#pragma clang fp contract(off)
    int g = blockIdx.x * 256 + threadIdx.x;      // 0..32767
    int b = g >> 12, j = g & 4095;
    const float* xb = xyz + (size_t)b * 3 * NPTS;
    float x = xb[j];
    float y = xb[NPTS + j];
    float z = xb[2 * NPTS + j];
    float sq = (x * x + y * y) + z * z;
    pts4g[g] = make_float4(x, y, z, sq);
}

// ---------------------------------------------------------------------------
// Kernel 1: transpose fp32 points [b][d][n] -> point-major P0[b][n][d],
// fused with stats[0] (per-channel sum / sumsq) accumulation.
// Grid: 8 b x 64 tiles of 64 points = 512 WGs, 256 threads.
// ---------------------------------------------------------------------------
__global__ __launch_bounds__(256) void cast_kernel(
        const float* __restrict__ pts,
        float* __restrict__ P0, float* __restrict__ stats0) {
    __shared__ __align__(16) float tr[64 * 65];      // [d][n] transpose tile (+1 pad)
    __shared__ float slotA[4 * 64], slotB[4 * 64];
    int wg = blockIdx.x;
    int b = wg >> 6;
    int n0 = (wg & 63) << 6;
    int tid = threadIdx.x;
    int lane6 = tid & 63;
    int grp = tid >> 6;              // 0..3

    #pragma unroll
    for (int k = 0; k < 16; ++k) {
        int d = grp + (k << 2);
        float v = pts[(((size_t)((b << 6) + d)) << 12) + n0 + lane6];
        tr[d * 65 + lane6] = v;
    }
    __syncthreads();
    int c = lane6;
    float s = 0.0f, s2 = 0.0f;
    #pragma unroll
    for (int k = 0; k < 16; ++k) {
        int p = grp + (k << 2);
        float v = tr[c * 65 + p];
        P0[((size_t)((b << 12) + n0 + p)) * 64 + c] = v;
        s += v; s2 += v * v;
    }
    slotA[grp * 64 + c] = s;
    slotB[grp * 64 + c] = s2;
    __syncthreads();
    if (tid < 64) {
        float t = slotA[tid] + slotA[64 + tid] + slotA[128 + tid] + slotA[192 + tid];
        atomicAdd(&stats0[tid], t);
    } else if (tid < 128) {
        int cc = tid - 64;
        float t = slotB[cc] + slotB[64 + cc] + slotB[128 + cc] + slotB[192 + cc];
        atomicAdd(&stats0[64 + cc], t);
    }
}

// ---------------------------------------------------------------------------
// Kernel 2: brute-force 8-NN, one QUERY per LANE (cuts insert divergence:
// the old (query,chunk)-per-lane layout ran the ~100-cyc sorted insert on
// ~85% of wave-steps). 8 waves/WG: wave = (qgrp 0..1, chunk 0..3); lane =
// query. Candidates for the whole batch staged in LDS (64 KB, broadcast
// b128 reads). Top-8 kept as f64 KEYS: key = f64(d2) | idx (12 low mantissa
// bits — order-preserving, ties -> lower idx under fmin, matching top_k
// stability). Insert = branch-gated pure fmin/fmax chain (15 f64 ops, no
// vcc, no index shuffling). 4 chunk-partials merged in-WG by key =
// lexicographic (d2, idx) = exact single-scan order (also preserves the
// reference's gather summation order).
// d2 formula matches numpy bit-for-bit: contract off, sequential dot,
// d2 = (sq_i - 2*dot) + sq_j.
// Grid: 8 b x 32 q-tiles of 128 = 256 WGs, 512 threads. LDS 100 KB.
// ---------------------------------------------------------------------------
__global__ __launch_bounds__(512) void knn_kernel(
        const float4* __restrict__ pts4g, int* __restrict__ idx) {
#pragma clang fp contract(off)
    __shared__ __align__(16) float4 cand[NPTS];      // 64 KB
    __shared__ double stash[128 * 36];               // [q][chunk][9], 36 KB
    int wg = blockIdx.x;
    int b = wg >> 5;
    int q0 = (wg & 31) << 7;
    int tid = threadIdx.x;                           // 0..511

    const float4* cb = pts4g + ((size_t)b << 12);
    #pragma unroll
    for (int k = 0; k < 8; ++k)
        cand[tid + (k << 9)] = cb[tid + (k << 9)];
    __syncthreads();

    int lane  = tid & 63;
    int wave  = tid >> 6;            // 0..7
    int chunk = wave & 3;            // candidate chunk
    int qgrp  = wave >> 2;           // 0..1
    int q_l   = (qgrp << 6) | lane;  // 0..127
    float4 qp = cand[q0 + q_l];

    double k0, k1, k2, k3, k4, k5, k6, k7;
    k0 = k1 = k2 = k3 = k4 = k5 = k6 = k7 = __builtin_inf();
    float bd7f = 3.4e38f;

    int jbase = chunk << 10;
    for (int jo = 0; jo < 1024; jo += 8) {
        float d2v[8];
        #pragma unroll
        for (int u = 0; u < 8; ++u) {
            float4 p = cand[jbase + jo + u];
            float dot = (qp.x * p.x + qp.y * p.y) + qp.z * p.z;
            d2v[u] = (qp.w - 2.0f * dot) + p.w;
        }
        #pragma unroll
        for (int u = 0; u < 8; ++u) {
            float d2 = d2v[u];
            if (d2 < bd7f) {
                unsigned long long kb =
                    __double_as_longlong((double)d2) |
                    (unsigned long long)(jbase + jo + u);
                double key = __longlong_as_double(kb);
                double n0 = fmin(k0, key);
                double n1 = fmin(k1, fmax(k0, key));
                double n2 = fmin(k2, fmax(k1, key));
                double n3 = fmin(k3, fmax(k2, key));
                double n4 = fmin(k4, fmax(k3, key));
                double n5 = fmin(k5, fmax(k4, key));
                double n6 = fmin(k6, fmax(k5, key));
                double n7 = fmin(k7, fmax(k6, key));
                k0 = n0; k1 = n1; k2 = n2; k3 = n3;
                k4 = n4; k5 = n5; k6 = n6; k7 = n7;
                bd7f = (float)k7;    // exact: idx bits << half-ulp of f32
            }
        }
    }

    {
        double* S = &stash[q_l * 36 + chunk * 9];
        S[0] = k0; S[1] = k1; S[2] = k2; S[3] = k3;
        S[4] = k4; S[5] = k5; S[6] = k6; S[7] = k7;
        S[8] = __builtin_inf();      // merge guard
    }
    __syncthreads();

    // 4-way merge per query by key (threads 0..127)
    if (tid < 128) {
        double* S = &stash[tid * 36];
        int h0 = 0, h1 = 0, h2 = 0, h3 = 0;
        int* op = idx + ((size_t)(b * NPTS + q0 + tid)) * 8;
        #pragma unroll
        for (int t = 0; t < 8; ++t) {
            double b0 = S[h0], b1 = S[9 + h1], b2 = S[18 + h2], b3 = S[27 + h3];
            double best = b0; int bc = 0;
            if (b1 < best) { best = b1; bc = 1; }
            if (b2 < best) { best = b2; bc = 2; }
            if (b3 < best) { best = b3; bc = 3; }
            h0 += (bc == 0); h1 += (bc == 1);
            h2 += (bc == 2); h3 += (bc == 3);
            op[t] = (int)(__double_as_longlong(best) & 0xFFFULL);
        }
    }
}

// ---------------------------------------------------------------------------
// Kernel 3 (x12): one residual block, fully fused.
//   - scale/shift from previous stats (BN affine + gamma folded)
//   - gather: m[d][pt] = (h_self + sum_8 h_nb)/9, h = lrelu(p*scale+shift)
//     via branchless fmax(h, 0.01h). Thread = (channel-quad, 4 points):
//     36 float4 loads/thread, fully unrolled -> deep outstanding-load
//     pipeline over L2 (each row read = 16 lanes x 16 B coalesced).
//   - GEMM 64x64 per point, fp32 VALU, 4x4 register tile
//   - residual add; write P_next; accumulate NEXT block's stats via
//     shuffle + LDS + global atomics
//   - last block: write fp32 output in [b][d][n] layout via LDS transpose
// Grid: 8 b x 64 tiles of 64 points = 512 WGs, 256 threads. LDS ~40 KB.
// ---------------------------------------------------------------------------
__global__ __launch_bounds__(256) void block_kernel(
        const float* __restrict__ Pin, float* __restrict__ Pout,
        const float* __restrict__ statsIn, float* __restrict__ statsOut,
        const float* __restrict__ Wp, const float* __restrict__ Bp,
        const float* __restrict__ Gp, const float* __restrict__ Betap,
        const int* __restrict__ gidx, float* __restrict__ dout, int last) {
    __shared__ __align__(16) float Wt[64 * 68];      // W transposed: Wt[d][o]
    __shared__ __align__(16) float mt[64 * 68];      // m[d][pt]
    __shared__ __align__(16) int   idxl[64 * 8];
    __shared__ __align__(16) float scale_l[64], shift_l[64], bias_l[64];
    __shared__ float slot[4 * 128];

    int wg = blockIdx.x;
    int b = wg >> 6;
    int n0 = (wg & 63) << 6;
    int tid = threadIdx.x;

    // --- setup: idx tile first (gather needs it), then W^T, BN affine ---
    if (tid < 128) {
        ((int4*)idxl)[tid] = ((const int4*)(gidx + ((size_t)(b * NPTS + n0)) * 8))[tid];
    }
    #pragma unroll
    for (int k = 0; k < 16; ++k) {
        int lin = tid + (k << 8);
        int o = lin >> 6, d = lin & 63;
        Wt[d * 68 + o] = Wp[lin];
    }
    if (tid < 64) {
        int c = tid;
        float sum = statsIn[c], sumsq = statsIn[64 + c];
        float mean = sum * (1.0f / 32768.0f);
        float var  = sumsq * (1.0f / 32768.0f) - mean * mean;
        float rs   = 1.0f / sqrtf(var + 1e-5f);
        float sc   = Gp[c] * rs;
        scale_l[c] = sc;
        shift_l[c] = Betap[c] - mean * sc;
        bias_l[c]  = Bp[c];
    }
    __syncthreads();

    // --- gather: m[d][pt], float4 over channels ---
    {
        int cq = tid & 15;           // channel quad: channels 4cq..4cq+3
        int pg = tid >> 4;           // 0..15: points 4pg..4pg+3
        float4 sc4 = *(const float4*)&scale_l[cq << 2];
        float4 sh4 = *(const float4*)&shift_l[cq << 2];
        const float* Pb = Pin + ((((size_t)b) << 12) << 6);
        #pragma unroll
        for (int i = 0; i < 4; ++i) {
            int pt = (pg << 2) + i;
            int4 ja = *(const int4*)&idxl[pt * 8];
            int4 jb = *(const int4*)&idxl[pt * 8 + 4];
            int rows[9];
            rows[0] = n0 + pt;
            rows[1] = ja.x; rows[2] = ja.y; rows[3] = ja.z; rows[4] = ja.w;
            rows[5] = jb.x; rows[6] = jb.y; rows[7] = jb.z; rows[8] = jb.w;
            float4 v[9];
            #pragma unroll
            for (int k = 0; k < 9; ++k)
                v[k] = *(const float4*)&Pb[(((size_t)rows[k]) << 6) + (cq << 2)];
            float4 a = make_float4(0.f, 0.f, 0.f, 0.f);
            #pragma unroll
            for (int k = 0; k < 9; ++k) {
                float hx = v[k].x * sc4.x + sh4.x;
                float hy = v[k].y * sc4.y + sh4.y;
                float hz = v[k].z * sc4.z + sh4.z;
                float hw = v[k].w * sc4.w + sh4.w;
                a.x += fmaxf(hx, 0.01f * hx);
                a.y += fmaxf(hy, 0.01f * hy);
                a.z += fmaxf(hz, 0.01f * hz);
                a.w += fmaxf(hw, 0.01f * hw);
            }
            int c0 = cq << 2;
            mt[(c0 + 0) * 68 + pt] = a.x * (1.0f / 9.0f);
            mt[(c0 + 1) * 68 + pt] = a.y * (1.0f / 9.0f);
            mt[(c0 + 2) * 68 + pt] = a.z * (1.0f / 9.0f);
            mt[(c0 + 3) * 68 + pt] = a.w * (1.0f / 9.0f);
        }
    }
    __syncthreads();

    // --- GEMM: out[pt][o] = sum_d Wt[d][o] * m[d][pt] + bias[o] ---
    int o0 = (tid & 15) << 2;
    int p0 = (tid >> 4) << 2;
    float4 acc[4];
    {
        float4 bias4 = *(const float4*)&bias_l[o0];
        acc[0] = bias4; acc[1] = bias4; acc[2] = bias4; acc[3] = bias4;
    }
    #pragma unroll
    for (int d = 0; d < 64; ++d) {
        float4 wv = *(const float4*)&Wt[d * 68 + o0];
        float4 a  = *(const float4*)&mt[d * 68 + p0];
        acc[0].x += wv.x * a.x; acc[0].y += wv.y * a.x; acc[0].z += wv.z * a.x; acc[0].w += wv.w * a.x;
        acc[1].x += wv.x * a.y; acc[1].y += wv.y * a.y; acc[1].z += wv.z * a.y; acc[1].w += wv.w * a.y;
        acc[2].x += wv.x * a.z; acc[2].y += wv.y * a.z; acc[2].z += wv.z * a.z; acc[2].w += wv.w * a.z;
        acc[3].x += wv.x * a.w; acc[3].y += wv.y * a.w; acc[3].z += wv.z * a.w; acc[3].w += wv.w * a.w;
    }

    // --- residual add ---
    const float* PbIn = Pin + ((((size_t)b) << 12) + n0) * 64;
    #pragma unroll
    for (int j = 0; j < 4; ++j) {
        float4 r = *(const float4*)&PbIn[((size_t)(p0 + j)) * 64 + o0];
        acc[j].x += r.x; acc[j].y += r.y; acc[j].z += r.z; acc[j].w += r.w;
    }

    if (!last) {
        float* PbOut = Pout + ((((size_t)b) << 12) + n0) * 64;
        #pragma unroll
        for (int j = 0; j < 4; ++j)
            *(float4*)&PbOut[((size_t)(p0 + j)) * 64 + o0] = acc[j];

        float4 s, s2;
        s.x = acc[0].x + acc[1].x + acc[2].x + acc[3].x;
        s.y = acc[0].y + acc[1].y + acc[2].y + acc[3].y;
        s.z = acc[0].z + acc[1].z + acc[2].z + acc[3].z;
        s.w = acc[0].w + acc[1].w + acc[2].w + acc[3].w;
        s2.x = acc[0].x*acc[0].x + acc[1].x*acc[1].x + acc[2].x*acc[2].x + acc[3].x*acc[3].x;
        s2.y = acc[0].y*acc[0].y + acc[1].y*acc[1].y + acc[2].y*acc[2].y + acc[3].y*acc[3].y;
        s2.z = acc[0].z*acc[0].z + acc[1].z*acc[1].z + acc[2].z*acc[2].z + acc[3].z*acc[3].z;
        s2.w = acc[0].w*acc[0].w + acc[1].w*acc[1].w + acc[2].w*acc[2].w + acc[3].w*acc[3].w;
        #pragma unroll
        for (int m = 16; m <= 32; m <<= 1) {
            s.x += __shfl_xor(s.x, m, 64);  s.y += __shfl_xor(s.y, m, 64);
            s.z += __shfl_xor(s.z, m, 64);  s.w += __shfl_xor(s.w, m, 64);
            s2.x += __shfl_xor(s2.x, m, 64); s2.y += __shfl_xor(s2.y, m, 64);
            s2.z += __shfl_xor(s2.z, m, 64); s2.w += __shfl_xor(s2.w, m, 64);
        }
        if ((tid & 63) < 16) {
            int w = tid >> 6;
            slot[w * 128 + o0 + 0] = s.x;  slot[w * 128 + o0 + 1] = s.y;
            slot[w * 128 + o0 + 2] = s.z;  slot[w * 128 + o0 + 3] = s.w;
            slot[w * 128 + 64 + o0 + 0] = s2.x; slot[w * 128 + 64 + o0 + 1] = s2.y;
            slot[w * 128 + 64 + o0 + 2] = s2.z; slot[w * 128 + 64 + o0 + 3] = s2.w;
        }
        __syncthreads();
        if (tid < 128) {
            float t = slot[tid] + slot[128 + tid] + slot[256 + tid] + slot[384 + tid];
            atomicAdd(&statsOut[tid], t);
        }
    } else {
        __syncthreads();                         // all mt reads done
        float* stage = mt;                       // reuse as [o][pt], 16 KB
        #pragma unroll
        for (int j = 0; j < 4; ++j) {
            stage[(o0 + 0) * 64 + p0 + j] = acc[j].x;
            stage[(o0 + 1) * 64 + p0 + j] = acc[j].y;
            stage[(o0 + 2) * 64 + p0 + j] = acc[j].z;
            stage[(o0 + 3) * 64 + p0 + j] = acc[j].w;
        }
        __syncthreads();
        #pragma unroll
        for (int k = 0; k < 16; ++k) {
            int lin = tid + (k << 8);
            int o = lin >> 6, pt = lin & 63;
            dout[(((size_t)((b << 6) + o)) << 12) + n0 + pt] = stage[lin];
        }
    }
}

// ---------------------------------------------------------------------------
extern "C" void kernel_launch(void* const* d_in, const int* in_sizes, int n_in,
                              void* d_out, int out_size, void* d_ws, size_t ws_size,
                              hipStream_t stream) {
    const float* xyz    = (const float*)d_in[0];
    const float* pts    = (const float*)d_in[1];
    const float* conv_w = (const float*)d_in[2];
    const float* conv_b = (const float*)d_in[3];
    const float* gamma  = (const float*)d_in[4];
    const float* beta   = (const float*)d_in[5];
    float* out = (float*)d_out;

    char* ws = (char*)d_ws;
    float*  P0    = (float*)(ws);                                  //  8 MB
    float*  P1    = (float*)(ws + (size_t)8 * 1024 * 1024);        //  8 MB
    int*    idx   = (int*)  (ws + (size_t)16 * 1024 * 1024);       //  1 MB
    float*  stats = (float*)(ws + (size_t)17 * 1024 * 1024);       // 6.5 KB
    float4* pts4g = (float4*)(ws + (size_t)18 * 1024 * 1024);      // 512 KB

    zero_stats_kernel<<<7, 256, 0, stream>>>(stats);
    prep_kernel<<<128, 256, 0, stream>>>(xyz, pts4g);
    cast_kernel<<<512, 256, 0, stream>>>(pts, P0, stats);
    knn_kernel<<<256, 512, 0, stream>>>(pts4g, idx);

    float* Pbuf[2] = {P0, P1};
    for (int t = 0; t < NBLK; ++t) {
        block_kernel<<<512, 256, 0, stream>>>(
            Pbuf[t & 1], Pbuf[(t + 1) & 1],
            stats + t * 128, stats + (t + 1) * 128,
            conv_w + (size_t)t * 4096, conv_b + (size_t)t * 64,
            gamma + (size_t)t * 64, beta + (size_t)t * 64,
            idx, out, (t == NBLK - 1) ? 1 : 0);
    }
}

// Round 5
// 326.744 us; speedup vs baseline: 2.6002x; 1.4745x over previous
//
#include <hip/hip_runtime.h>
#include <hip/hip_bf16.h>

// Problem constants
#define NB     8
#define NPTS   4096
#define DIMC   64
#define KNN_K  8
#define NBLK   12
#define NREP   8      // stats replicas (atomic de-contention)

// ---------------------------------------------------------------------------
// Kernel 0: zero the stats buffers (13 stages x 8 replicas x 128 floats).
// ws is poisoned with 0xAA before every timed launch — re-zero every call.
// ---------------------------------------------------------------------------
__global__ void zero_stats_kernel(float* __restrict__ stats) {
    int i = threadIdx.x + blockIdx.x * 256;
    if (i < 13 * NREP * 128) stats[i] = 0.0f;
}

// ---------------------------------------------------------------------------
// Kernel 0b: precompute (x, y, z, |x|^2) per point for the KNN kernel.
// sq formula matches numpy bit-for-bit (contract off, sequential adds).
// ---------------------------------------------------------------------------
__global__ __launch_bounds__(256) void prep_kernel(
        const float* __restrict__ xyz, float4* __restrict__ pts4g) {
#pragma clang fp contract(off)
    int g = blockIdx.x * 256 + threadIdx.x;      // 0..32767
    int b = g >> 12, j = g & 4095;
    const float* xb = xyz + (size_t)b * 3 * NPTS;
    float x = xb[j];
    float y = xb[NPTS + j];
    float z = xb[2 * NPTS + j];
    float sq = (x * x + y * y) + z * z;
    pts4g[g] = make_float4(x, y, z, sq);
}

// ---------------------------------------------------------------------------
// Kernel 1: transpose fp32 points [b][d][n] -> point-major P0[b][n][d],
// fused with stats[0] accumulation. XCD-affine: b = blockIdx & 7 so batch
// b's P-slice is written from XCD b's CUs and stays in its L2 for the
// block kernels (blockIdx%8 -> XCD round-robin heuristic).
// Grid: 512 WGs, 256 threads.
// ---------------------------------------------------------------------------
__global__ __launch_bounds__(256) void cast_kernel(
        const float* __restrict__ pts,
        float* __restrict__ P0, float* __restrict__ stats0) {
    __shared__ __align__(16) float tr[64 * 65];      // [d][n] transpose tile (+1 pad)
    __shared__ float slotA[4 * 64], slotB[4 * 64];
    int wg = blockIdx.x;
    int b = wg & 7;                  // XCD affinity
    int n0 = (wg >> 3) << 6;
    int rep = (wg >> 3) & (NREP - 1);
    int tid = threadIdx.x;
    int lane6 = tid & 63;
    int grp = tid >> 6;              // 0..3

    #pragma unroll
    for (int k = 0; k < 16; ++k) {
        int d = grp + (k << 2);
        float v = pts[(((size_t)((b << 6) + d)) << 12) + n0 + lane6];
        tr[d * 65 + lane6] = v;
    }
    __syncthreads();
    int c = lane6;
    float s = 0.0f, s2 = 0.0f;
    #pragma unroll
    for (int k = 0; k < 16; ++k) {
        int p = grp + (k << 2);
        float v = tr[c * 65 + p];
        P0[((size_t)((b << 12) + n0 + p)) * 64 + c] = v;
        s += v; s2 += v * v;
    }
    slotA[grp * 64 + c] = s;
    slotB[grp * 64 + c] = s2;
    __syncthreads();
    if (tid < 64) {
        float t = slotA[tid] + slotA[64 + tid] + slotA[128 + tid] + slotA[192 + tid];
        atomicAdd(&stats0[rep * 128 + tid], t);
    } else if (tid < 128) {
        int cc = tid - 64;
        float t = slotB[cc] + slotB[64 + cc] + slotB[128 + cc] + slotB[192 + cc];
        atomicAdd(&stats0[rep * 128 + 64 + cc], t);
    }
}

// ---------------------------------------------------------------------------
// Kernel 2: brute-force 8-NN, one query per lane, f64-key top-8.
// Candidates staged in 2048-point HALVES (32 KB vs 64 KB) so LDS = 68 KB
// -> 2 WGs/CU -> 4 waves/SIMD (was 1 WG, 73% VALUBusy). Chunk c scans
// [512c, 512c+512) of each half: per-chunk scan order stays ascending-j,
// so the 4-way key merge still reproduces the exact single-scan order.
// key = f64(d2) | idx (12 low mantissa bits; order-preserving, ties ->
// lower idx, matching top_k stability). Insert = branch-gated fmin/fmax
// chain. Stash layout [(c*9+t)*128+q]: lanes -> consecutive doubles
// (conflict-free). d2 formula matches numpy bit-for-bit.
// Grid: 8 b x 32 q-tiles of 128 = 256 WGs, 512 threads.
// ---------------------------------------------------------------------------
__global__ __launch_bounds__(512) void knn_kernel(
        const float4* __restrict__ pts4g, int* __restrict__ idx) {
#pragma clang fp contract(off)
    __shared__ __align__(16) float4 cand[2048];      // 32 KB
    __shared__ double stash[4 * 9 * 128];            // 36 KB
    int wg = blockIdx.x;
    int b = wg >> 5;
    int q0 = (wg & 31) << 7;
    int tid = threadIdx.x;                           // 0..511

    int lane  = tid & 63;
    int wave  = tid >> 6;            // 0..7
    int chunk = wave & 3;
    int qgrp  = wave >> 2;           // 0..1
    int q_l   = (qgrp << 6) | lane;  // 0..127

    const float4* cb = pts4g + ((size_t)b << 12);
    float4 qp = cb[q0 + q_l];

    double k0, k1, k2, k3, k4, k5, k6, k7;
    k0 = k1 = k2 = k3 = k4 = k5 = k6 = k7 = __builtin_inf();
    float bd7f = 3.4e38f;

    for (int half = 0; half < 2; ++half) {
        if (half) __syncthreads();                   // drain readers before restage
        #pragma unroll
        for (int k = 0; k < 4; ++k)
            cand[tid + (k << 9)] = cb[(half << 11) + tid + (k << 9)];
        __syncthreads();

        int jl0 = chunk << 9;                        // local staged offset
        int jg0 = (half << 11) | (chunk << 9);       // global candidate index
        for (int jo = 0; jo < 512; jo += 8) {
            float d2v[8];
            #pragma unroll
            for (int u = 0; u < 8; ++u) {
                float4 p = cand[jl0 + jo + u];
                float dot = (qp.x * p.x + qp.y * p.y) + qp.z * p.z;
                d2v[u] = (qp.w - 2.0f * dot) + p.w;
            }
            #pragma unroll
            for (int u = 0; u < 8; ++u) {
                float d2 = d2v[u];
                if (d2 < bd7f) {
                    unsigned long long kb =
                        __double_as_longlong((double)d2) |
                        (unsigned long long)(jg0 + jo + u);
                    double key = __longlong_as_double(kb);
                    double n0 = fmin(k0, key);
                    double n1 = fmin(k1, fmax(k0, key));
                    double n2 = fmin(k2, fmax(k1, key));
                    double n3 = fmin(k3, fmax(k2, key));
                    double n4 = fmin(k4, fmax(k3, key));
                    double n5 = fmin(k5, fmax(k4, key));
                    double n6 = fmin(k6, fmax(k5, key));
                    double n7 = fmin(k7, fmax(k6, key));
                    k0 = n0; k1 = n1; k2 = n2; k3 = n3;
                    k4 = n4; k5 = n5; k6 = n6; k7 = n7;
                    bd7f = (float)k7;    // exact: idx bits << half-ulp of f32
                }
            }
        }
    }

    {
        double* S = &stash[(chunk * 9) * 128 + q_l];
        S[0 * 128] = k0; S[1 * 128] = k1; S[2 * 128] = k2; S[3 * 128] = k3;
        S[4 * 128] = k4; S[5 * 128] = k5; S[6 * 128] = k6; S[7 * 128] = k7;
        S[8 * 128] = __builtin_inf();    // merge guard
    }
    __syncthreads();

    // 4-way merge per query by key (threads 0..127)
    if (tid < 128) {
        int h0 = 0, h1 = 0, h2 = 0, h3 = 0;
        int* op = idx + ((size_t)(b * NPTS + q0 + tid)) * 8;
        #pragma unroll
        for (int t = 0; t < 8; ++t) {
            double b0 = stash[(0 * 9 + h0) * 128 + tid];
            double b1 = stash[(1 * 9 + h1) * 128 + tid];
            double b2 = stash[(2 * 9 + h2) * 128 + tid];
            double b3 = stash[(3 * 9 + h3) * 128 + tid];
            double best = b0; int bc = 0;
            if (b1 < best) { best = b1; bc = 1; }
            if (b2 < best) { best = b2; bc = 2; }
            if (b3 < best) { best = b3; bc = 3; }
            h0 += (bc == 0); h1 += (bc == 1);
            h2 += (bc == 2); h3 += (bc == 3);
            op[t] = (int)(__double_as_longlong(best) & 0xFFFULL);
        }
    }
}

// ---------------------------------------------------------------------------
// Kernel 3 (x12): one residual block, fully fused. XCD-affine b = wg & 7:
// batch b's P slices live in XCD b's L2 (written there by cast/previous
// block) -> the 8-neighbor gather hits local L2 instead of LLC.
//   - self rows staged once in LDS (serves h_self AND the residual;
//     cuts 36 -> 32 global loads/thread and 16 MB/kernel of re-reads)
//   - BN affine from 8-replica stats (summed here)
//   - GEMM 64x64 per point, fp32 VALU, 4x4 register tile
//   - stats for NEXT block -> replica (wg>>3)&7 (64-way contention, not 512)
//   - last block: fp32 output in [b][d][n] via LDS transpose
// Grid: 512 WGs (64 tiles x 8 b), 256 threads. LDS ~54 KB -> 2 WG/CU.
// ---------------------------------------------------------------------------
__global__ __launch_bounds__(256) void block_kernel(
        const float* __restrict__ Pin, float* __restrict__ Pout,
        const float* __restrict__ statsIn, float* __restrict__ statsOut,
        const float* __restrict__ Wp, const float* __restrict__ Bp,
        const float* __restrict__ Gp, const float* __restrict__ Betap,
        const int* __restrict__ gidx, float* __restrict__ dout, int last) {
    __shared__ __align__(16) float Wt[64 * 68];      // W transposed: Wt[d][o]
    __shared__ __align__(16) float mt[64 * 68];      // m[d][pt]
    __shared__ __align__(16) float selft[64 * 64];   // raw self rows [pt][c]
    __shared__ __align__(16) int   idxl[64 * 8];
    __shared__ __align__(16) float scale_l[64], shift_l[64], bias_l[64];
    __shared__ float slot[4 * 128];

    int wg = blockIdx.x;
    int b = wg & 7;                  // XCD affinity
    int n0 = (wg >> 3) << 6;
    int rep = (wg >> 3) & (NREP - 1);
    int tid = threadIdx.x;

    const float* Pb = Pin + (((size_t)b) << 18);     // batch slice [4096][64]

    // --- setup: idx tile, self tile, W^T, BN affine (replica-summed) ---
    if (tid < 128) {
        ((int4*)idxl)[tid] = ((const int4*)(gidx + ((size_t)(b * NPTS + n0)) * 8))[tid];
    }
    #pragma unroll
    for (int k = 0; k < 4; ++k) {    // self rows: 64 pts x 64 ch, coalesced
        int lin = tid + (k << 8);    // float4 id
        ((float4*)selft)[lin] = ((const float4*)&Pb[(size_t)n0 << 6])[lin];
    }
    #pragma unroll
    for (int k = 0; k < 16; ++k) {
        int lin = tid + (k << 8);
        int o = lin >> 6, d = lin & 63;
        Wt[d * 68 + o] = Wp[lin];
    }
    if (tid < 64) {
        int c = tid;
        float sum = 0.0f, sumsq = 0.0f;
        #pragma unroll
        for (int r = 0; r < NREP; ++r) {
            sum   += statsIn[r * 128 + c];
            sumsq += statsIn[r * 128 + 64 + c];
        }
        float mean = sum * (1.0f / 32768.0f);
        float var  = sumsq * (1.0f / 32768.0f) - mean * mean;
        float rs   = 1.0f / sqrtf(var + 1e-5f);
        float sc   = Gp[c] * rs;
        scale_l[c] = sc;
        shift_l[c] = Betap[c] - mean * sc;
        bias_l[c]  = Bp[c];
    }
    __syncthreads();

    // --- gather: m[d][pt]; self from LDS, 8 neighbors from (local-L2) global ---
    {
        int cq = tid & 15;           // channel quad: channels 4cq..4cq+3
        int pg = tid >> 4;           // 0..15: points 4pg..4pg+3
        int c4 = cq << 2;
        float4 sc4 = *(const float4*)&scale_l[c4];
        float4 sh4 = *(const float4*)&shift_l[c4];
        #pragma unroll
        for (int i = 0; i < 4; ++i) {
            int pt = (pg << 2) + i;
            int4 ja = *(const int4*)&idxl[pt * 8];
            int4 jb = *(const int4*)&idxl[pt * 8 + 4];
            float4 v[9];
            v[0] = *(const float4*)&selft[(pt << 6) + c4];
            v[1] = *(const float4*)&Pb[(((size_t)ja.x) << 6) + c4];
            v[2] = *(const float4*)&Pb[(((size_t)ja.y) << 6) + c4];
            v[3] = *(const float4*)&Pb[(((size_t)ja.z) << 6) + c4];
            v[4] = *(const float4*)&Pb[(((size_t)ja.w) << 6) + c4];
            v[5] = *(const float4*)&Pb[(((size_t)jb.x) << 6) + c4];
            v[6] = *(const float4*)&Pb[(((size_t)jb.y) << 6) + c4];
            v[7] = *(const float4*)&Pb[(((size_t)jb.z) << 6) + c4];
            v[8] = *(const float4*)&Pb[(((size_t)jb.w) << 6) + c4];
            float4 a = make_float4(0.f, 0.f, 0.f, 0.f);
            #pragma unroll
            for (int k = 0; k < 9; ++k) {
                float hx = v[k].x * sc4.x + sh4.x;
                float hy = v[k].y * sc4.y + sh4.y;
                float hz = v[k].z * sc4.z + sh4.z;
                float hw = v[k].w * sc4.w + sh4.w;
                a.x += fmaxf(hx, 0.01f * hx);
                a.y += fmaxf(hy, 0.01f * hy);
                a.z += fmaxf(hz, 0.01f * hz);
                a.w += fmaxf(hw, 0.01f * hw);
            }
            mt[(c4 + 0) * 68 + pt] = a.x * (1.0f / 9.0f);
            mt[(c4 + 1) * 68 + pt] = a.y * (1.0f / 9.0f);
            mt[(c4 + 2) * 68 + pt] = a.z * (1.0f / 9.0f);
            mt[(c4 + 3) * 68 + pt] = a.w * (1.0f / 9.0f);
        }
    }
    __syncthreads();

    // --- GEMM: out[pt][o] = sum_d Wt[d][o] * m[d][pt] + bias[o] ---
    int o0 = (tid & 15) << 2;
    int p0 = (tid >> 4) << 2;
    float4 acc[4];
    {
        float4 bias4 = *(const float4*)&bias_l[o0];
        acc[0] = bias4; acc[1] = bias4; acc[2] = bias4; acc[3] = bias4;
    }
    #pragma unroll
    for (int d = 0; d < 64; ++d) {
        float4 wv = *(const float4*)&Wt[d * 68 + o0];
        float4 a  = *(const float4*)&mt[d * 68 + p0];
        acc[0].x += wv.x * a.x; acc[0].y += wv.y * a.x; acc[0].z += wv.z * a.x; acc[0].w += wv.w * a.x;
        acc[1].x += wv.x * a.y; acc[1].y += wv.y * a.y; acc[1].z += wv.z * a.y; acc[1].w += wv.w * a.y;
        acc[2].x += wv.x * a.z; acc[2].y += wv.y * a.z; acc[2].z += wv.z * a.z; acc[2].w += wv.w * a.z;
        acc[3].x += wv.x * a.w; acc[3].y += wv.y * a.w; acc[3].z += wv.z * a.w; acc[3].w += wv.w * a.w;
    }

    // --- residual add (self rows from LDS) ---
    #pragma unroll
    for (int j = 0; j < 4; ++j) {
        float4 r = *(const float4*)&selft[((p0 + j) << 6) + o0];
        acc[j].x += r.x; acc[j].y += r.y; acc[j].z += r.z; acc[j].w += r.w;
    }

    if (!last) {
        float* PbOut = Pout + ((((size_t)b) << 12) + n0) * 64;
        #pragma unroll
        for (int j = 0; j < 4; ++j)
            *(float4*)&PbOut[((size_t)(p0 + j)) * 64 + o0] = acc[j];

        float4 s, s2;
        s.x = acc[0].x + acc[1].x + acc[2].x + acc[3].x;
        s.y = acc[0].y + acc[1].y + acc[2].y + acc[3].y;
        s.z = acc[0].z + acc[1].z + acc[2].z + acc[3].z;
        s.w = acc[0].w + acc[1].w + acc[2].w + acc[3].w;
        s2.x = acc[0].x*acc[0].x + acc[1].x*acc[1].x + acc[2].x*acc[2].x + acc[3].x*acc[3].x;
        s2.y = acc[0].y*acc[0].y + acc[1].y*acc[1].y + acc[2].y*acc[2].y + acc[3].y*acc[3].y;
        s2.z = acc[0].z*acc[0].z + acc[1].z*acc[1].z + acc[2].z*acc[2].z + acc[3].z*acc[3].z;
        s2.w = acc[0].w*acc[0].w + acc[1].w*acc[1].w + acc[2].w*acc[2].w + acc[3].w*acc[3].w;
        #pragma unroll
        for (int m = 16; m <= 32; m <<= 1) {
            s.x += __shfl_xor(s.x, m, 64);  s.y += __shfl_xor(s.y, m, 64);
            s.z += __shfl_xor(s.z, m, 64);  s.w += __shfl_xor(s.w, m, 64);
            s2.x += __shfl_xor(s2.x, m, 64); s2.y += __shfl_xor(s2.y, m, 64);
            s2.z += __shfl_xor(s2.z, m, 64); s2.w += __shfl_xor(s2.w, m, 64);
        }
        if ((tid & 63) < 16) {
            int w = tid >> 6;
            slot[w * 128 + o0 + 0] = s.x;  slot[w * 128 + o0 + 1] = s.y;
            slot[w * 128 + o0 + 2] = s.z;  slot[w * 128 + o0 + 3] = s.w;
            slot[w * 128 + 64 + o0 + 0] = s2.x; slot[w * 128 + 64 + o0 + 1] = s2.y;
            slot[w * 128 + 64 + o0 + 2] = s2.z; slot[w * 128 + 64 + o0 + 3] = s2.w;
        }
        __syncthreads();
        if (tid < 128) {
            float t = slot[tid] + slot[128 + tid] + slot[256 + tid] + slot[384 + tid];
            atomicAdd(&statsOut[rep * 128 + tid], t);
        }
    } else {
        __syncthreads();                         // all mt reads done
        float* stage = mt;                       // reuse as [o][pt], 16 KB
        #pragma unroll
        for (int j = 0; j < 4; ++j) {
            stage[(o0 + 0) * 64 + p0 + j] = acc[j].x;
            stage[(o0 + 1) * 64 + p0 + j] = acc[j].y;
            stage[(o0 + 2) * 64 + p0 + j] = acc[j].z;
            stage[(o0 + 3) * 64 + p0 + j] = acc[j].w;
        }
        __syncthreads();
        #pragma unroll
        for (int k = 0; k < 16; ++k) {
            int lin = tid + (k << 8);
            int o = lin >> 6, pt = lin & 63;
            dout[(((size_t)((b << 6) + o)) << 12) + n0 + pt] = stage[lin];
        }
    }
}

// ---------------------------------------------------------------------------
extern "C" void kernel_launch(void* const* d_in, const int* in_sizes, int n_in,
                              void* d_out, int out_size, void* d_ws, size_t ws_size,
                              hipStream_t stream) {
    const float* xyz    = (const float*)d_in[0];
    const float* pts    = (const float*)d_in[1];
    const float* conv_w = (const float*)d_in[2];
    const float* conv_b = (const float*)d_in[3];
    const float* gamma  = (const float*)d_in[4];
    const float* beta   = (const float*)d_in[5];
    float* out = (float*)d_out;

    char* ws = (char*)d_ws;
    float*  P0    = (float*)(ws);                                  //  8 MB
    float*  P1    = (float*)(ws + (size_t)8 * 1024 * 1024);        //  8 MB
    int*    idx   = (int*)  (ws + (size_t)16 * 1024 * 1024);       //  1 MB
    float*  stats = (float*)(ws + (size_t)17 * 1024 * 1024);       // 52 KB
    float4* pts4g = (float4*)(ws + (size_t)18 * 1024 * 1024);      // 512 KB

    zero_stats_kernel<<<52, 256, 0, stream>>>(stats);
    prep_kernel<<<128, 256, 0, stream>>>(xyz, pts4g);
    cast_kernel<<<512, 256, 0, stream>>>(pts, P0, stats);
    knn_kernel<<<256, 512, 0, stream>>>(pts4g, idx);

    float* Pbuf[2] = {P0, P1};
    for (int t = 0; t < NBLK; ++t) {
        block_kernel<<<512, 256, 0, stream>>>(
            Pbuf[t & 1], Pbuf[(t + 1) & 1],
            stats + (size_t)t * NREP * 128, stats + (size_t)(t + 1) * NREP * 128,
            conv_w + (size_t)t * 4096, conv_b + (size_t)t * 64,
            gamma + (size_t)t * 64, beta + (size_t)t * 64,
            idx, out, (t == NBLK - 1) ? 1 : 0);
    }
}